// Round 4
// baseline (704.464 us; speedup 1.0000x reference)
//
#include <hip/hip_runtime.h>

#define NODES 50000
#define RELS  3
#define NEDGE 600000
#define FIN   128
#define FHID  64
#define FOUT  64
#define SEGS  (RELS * NODES)            // 150000 (rel, dst) segments
#define NBLK  ((SEGS + 255) / 256)      // 586 scan blocks

// ---------------- degree counting (int) ----------------
__global__ __launch_bounds__(256) void deg_kernel(const int* __restrict__ src,
                                                  const int* __restrict__ dst,
                                                  int* __restrict__ odI,
                                                  int* __restrict__ idI) {
    int e = blockIdx.x * 256 + threadIdx.x;
    int r = blockIdx.y;
    if (e >= NEDGE) return;
    atomicAdd(&odI[r * NODES + src[r * NEDGE + e]], 1);
    atomicAdd(&idI[r * NODES + dst[r * NEDGE + e]], 1);
}

// ---------------- norms from int degrees ----------------
__global__ __launch_bounds__(256) void norm_kernel(const int* __restrict__ odI,
                                                   const int* __restrict__ idI,
                                                   float* __restrict__ outnorm,
                                                   float* __restrict__ innorm) {
    int i = blockIdx.x * 256 + threadIdx.x;
    if (i >= SEGS) return;
    outnorm[i] = 1.0f / sqrtf(fmaxf((float)odI[i], 1.0f));
    innorm[i]  = 1.0f / sqrtf(fmaxf((float)idI[i], 1.0f));
}

// ---------------- exclusive scan over idI (3 kernels) ----------------
__global__ __launch_bounds__(256) void scan_sums_kernel(const int* __restrict__ idI,
                                                        int* __restrict__ partials) {
    __shared__ int s[256];
    int i = blockIdx.x * 256 + threadIdx.x;
    s[threadIdx.x] = (i < SEGS) ? idI[i] : 0;
    __syncthreads();
    for (int off = 128; off > 0; off >>= 1) {
        if (threadIdx.x < off) s[threadIdx.x] += s[threadIdx.x + off];
        __syncthreads();
    }
    if (threadIdx.x == 0) partials[blockIdx.x] = s[0];
}

__global__ __launch_bounds__(1024) void scan_partials_kernel(int* __restrict__ partials) {
    __shared__ int s[1024];
    int tid = threadIdx.x;
    int v = (tid < NBLK) ? partials[tid] : 0;
    s[tid] = v;
    __syncthreads();
    for (int off = 1; off < 1024; off <<= 1) {
        int t = s[tid];
        int add = (tid >= off) ? s[tid - off] : 0;
        __syncthreads();
        s[tid] = t + add;
        __syncthreads();
    }
    if (tid < NBLK) partials[tid] = s[tid] - v;   // exclusive
}

__global__ __launch_bounds__(256) void scan_write_kernel(const int* __restrict__ idI,
                                                         const int* __restrict__ partials,
                                                         int* __restrict__ offs) {
    __shared__ int s[256];
    int tid = threadIdx.x;
    int i = blockIdx.x * 256 + tid;
    int v = (i < SEGS) ? idI[i] : 0;
    s[tid] = v;
    __syncthreads();
    for (int off = 1; off < 256; off <<= 1) {
        int t = s[tid];
        int add = (tid >= off) ? s[tid - off] : 0;
        __syncthreads();
        s[tid] = t + add;
        __syncthreads();
    }
    if (i < SEGS) offs[i] = partials[blockIdx.x] + (s[tid] - v);
}

// ---------------- CSR fill: bucket src ids by (rel,dst) ----------------
__global__ __launch_bounds__(256) void fill_kernel(const int* __restrict__ src,
                                                   const int* __restrict__ dst,
                                                   const int* __restrict__ offs,
                                                   int* __restrict__ cursor,
                                                   int* __restrict__ edge_src) {
    int e = blockIdx.x * 256 + threadIdx.x;
    int r = blockIdx.y;
    if (e >= NEDGE) return;
    int seg = r * NODES + dst[r * NEDGE + e];
    int pos = offs[seg] + atomicAdd(&cursor[seg], 1);
    edge_src[pos] = src[r * NEDGE + e];
}

// ---------------- layer 1 GEMM: h[r][n][j] = (x[n,:].W1[r][:,j]) * outnorm[r][n]
// 16 rows per thread (wave = 16 nodes x 64 cols): 4 ds_read_b32 serve 64 FMAs
// -> per-CU LDS port no longer oversubscribed; 16 independent x loads per k4.
__global__ __launch_bounds__(256) void gemm1_kernel(const float* __restrict__ x,
                                                    const float* __restrict__ W1,
                                                    const float* __restrict__ outnorm,
                                                    float* __restrict__ h) {
    __shared__ float Wl[FIN * FHID];          // 32 KB
    int r = blockIdx.y;
    const float4* Wr4 = (const float4*)(W1 + (size_t)r * FIN * FHID);
    float4* Wl4 = (float4*)Wl;
#pragma unroll
    for (int i = 0; i < 8; ++i) Wl4[threadIdx.x + i * 256] = Wr4[threadIdx.x + i * 256];
    __syncthreads();
    int j = threadIdx.x & 63;
    int w = threadIdx.x >> 6;
    int n0 = (blockIdx.x * 4 + w) * 16;
    if (n0 + 16 > NODES) n0 = NODES - 16;     // tail waves redo rows (same values)
    const float* xb = x + (size_t)n0 * FIN;
    float acc[16];
#pragma unroll
    for (int i = 0; i < 16; ++i) acc[i] = 0.f;
#pragma unroll 1
    for (int k4 = 0; k4 < FIN / 4; ++k4) {
        float4 a[16];
#pragma unroll
        for (int i = 0; i < 16; ++i)
            a[i] = *(const float4*)(xb + (size_t)i * FIN + k4 * 4);
        const float* wp = Wl + k4 * 4 * FHID + j;
        float w0 = wp[0], w1 = wp[FHID], w2 = wp[2 * FHID], w3 = wp[3 * FHID];
#pragma unroll
        for (int i = 0; i < 16; ++i) {
            acc[i] = fmaf(a[i].x, w0, acc[i]);
            acc[i] = fmaf(a[i].y, w1, acc[i]);
            acc[i] = fmaf(a[i].z, w2, acc[i]);
            acc[i] = fmaf(a[i].w, w3, acc[i]);
        }
    }
    const float* on = outnorm + r * NODES + n0;
    float* hb = h + ((size_t)r * NODES + n0) * FHID + j;
#pragma unroll
    for (int i = 0; i < 16; ++i) hb[(size_t)i * FHID] = acc[i] * on[i];
}

// ---------------- layer 1 gather ----------------
// One wave per dst node; lanes = 4 edges x 16 float4-slots. 1 KB gathered/instr.
__global__ __launch_bounds__(256) void gather1_kernel(const float* __restrict__ h,
                                                      const int* __restrict__ es,
                                                      const int* __restrict__ offs,
                                                      const int* __restrict__ cnt,
                                                      const float* __restrict__ innorm,
                                                      const float* __restrict__ b1,
                                                      float* __restrict__ B) {
    int lane = threadIdx.x & 63;
    int wv   = threadIdx.x >> 6;
    int d    = blockIdx.x * 4 + wv;           // NODES % 4 == 0
    int q    = lane & 15;                     // float4 slot within row
    int e4   = lane >> 4;                     // which of 4 edges
    float4 tot = {0.f, 0.f, 0.f, 0.f};
#pragma unroll
    for (int r = 0; r < RELS; ++r) {
        int seg = r * NODES + d;
        int o = offs[seg], c = cnt[seg];
        const float* Ar = h + (size_t)r * NODES * FHID;
        float4 s = {0.f, 0.f, 0.f, 0.f};
        int t = 0;
#pragma unroll 4
        for (; t + 4 <= c; t += 4) {
            int idx = es[o + t + e4];
            float4 v = *(const float4*)(Ar + (size_t)idx * FHID + q * 4);
            s.x += v.x; s.y += v.y; s.z += v.z; s.w += v.w;
        }
        int rem = c - t;
        if (e4 < rem) {
            int idx = es[o + t + e4];
            float4 v = *(const float4*)(Ar + (size_t)idx * FHID + q * 4);
            s.x += v.x; s.y += v.y; s.z += v.z; s.w += v.w;
        }
        float inr = innorm[seg];
        tot.x = fmaf(inr, s.x, tot.x); tot.y = fmaf(inr, s.y, tot.y);
        tot.z = fmaf(inr, s.z, tot.z); tot.w = fmaf(inr, s.w, tot.w);
    }
    // reduce across the 4 edge groups (lanes differing in bits 4,5)
    tot.x += __shfl_xor(tot.x, 16); tot.y += __shfl_xor(tot.y, 16);
    tot.z += __shfl_xor(tot.z, 16); tot.w += __shfl_xor(tot.w, 16);
    tot.x += __shfl_xor(tot.x, 32); tot.y += __shfl_xor(tot.y, 32);
    tot.z += __shfl_xor(tot.z, 32); tot.w += __shfl_xor(tot.w, 32);
    if (lane < 16) {
        float4 bs0 = ((const float4*)b1)[q];
        float4 bs1 = ((const float4*)(b1 + FHID))[q];
        float4 bs2 = ((const float4*)(b1 + 2 * FHID))[q];
        float4 o4;
        o4.x = fmaxf(tot.x + bs0.x + bs1.x + bs2.x, 0.f);
        o4.y = fmaxf(tot.y + bs0.y + bs1.y + bs2.y, 0.f);
        o4.z = fmaxf(tot.z + bs0.z + bs1.z + bs2.z, 0.f);
        o4.w = fmaxf(tot.w + bs0.w + bs1.w + bs2.w, 0.f);
        *(float4*)(B + (size_t)d * FHID + q * 4) = o4;
    }
}

// ---------------- layer 2 gather: A[r][d][j] = innorm[r][d]*sum_e outnorm[r][src]*h1[src][j]
__global__ __launch_bounds__(256) void gather2_kernel(const float* __restrict__ h1,
                                                      const int* __restrict__ es,
                                                      const int* __restrict__ offs,
                                                      const int* __restrict__ cnt,
                                                      const float* __restrict__ outnorm,
                                                      const float* __restrict__ innorm,
                                                      float* __restrict__ A) {
    int lane = threadIdx.x & 63;
    int wv   = threadIdx.x >> 6;
    int d    = blockIdx.x * 4 + wv;
    int r    = blockIdx.y;
    int q    = lane & 15;
    int e4   = lane >> 4;
    int seg = r * NODES + d;
    int o = offs[seg], c = cnt[seg];
    const float* on = outnorm + r * NODES;
    float4 s = {0.f, 0.f, 0.f, 0.f};
    int t = 0;
#pragma unroll 4
    for (; t + 4 <= c; t += 4) {
        int idx = es[o + t + e4];
        float w = on[idx];
        float4 v = *(const float4*)(h1 + (size_t)idx * FHID + q * 4);
        s.x = fmaf(w, v.x, s.x); s.y = fmaf(w, v.y, s.y);
        s.z = fmaf(w, v.z, s.z); s.w = fmaf(w, v.w, s.w);
    }
    int rem = c - t;
    if (e4 < rem) {
        int idx = es[o + t + e4];
        float w = on[idx];
        float4 v = *(const float4*)(h1 + (size_t)idx * FHID + q * 4);
        s.x = fmaf(w, v.x, s.x); s.y = fmaf(w, v.y, s.y);
        s.z = fmaf(w, v.z, s.z); s.w = fmaf(w, v.w, s.w);
    }
    s.x += __shfl_xor(s.x, 16); s.y += __shfl_xor(s.y, 16);
    s.z += __shfl_xor(s.z, 16); s.w += __shfl_xor(s.w, 16);
    s.x += __shfl_xor(s.x, 32); s.y += __shfl_xor(s.y, 32);
    s.z += __shfl_xor(s.z, 32); s.w += __shfl_xor(s.w, 32);
    if (lane < 16) {
        float inr = innorm[seg];
        float4 o4 = {inr * s.x, inr * s.y, inr * s.z, inr * s.w};
        *(float4*)(A + (size_t)seg * FHID + q * 4) = o4;
    }
}

// ---------------- layer 2 GEMM + combine: out = sum_r A[r] @ W2[r] + sum_r b2[r]
// 16 rows per thread, same LDS-port-balanced structure as gemm1.
__global__ __launch_bounds__(256) void out_kernel(const float* __restrict__ agg2,
                                                  const float* __restrict__ W2,
                                                  const float* __restrict__ b2,
                                                  float* __restrict__ out) {
    __shared__ float Wl[RELS * FHID * FOUT];  // 48 KB
    float4* Wl4 = (float4*)Wl;
    const float4* Wr4 = (const float4*)W2;
#pragma unroll
    for (int i = 0; i < 12; ++i) Wl4[threadIdx.x + i * 256] = Wr4[threadIdx.x + i * 256];
    __syncthreads();
    int j = threadIdx.x & 63;
    int w = threadIdx.x >> 6;
    int n0 = (blockIdx.x * 4 + w) * 16;
    if (n0 + 16 > NODES) n0 = NODES - 16;
    float bsum = b2[j] + b2[FOUT + j] + b2[2 * FOUT + j];
    float acc[16];
#pragma unroll
    for (int i = 0; i < 16; ++i) acc[i] = bsum;
#pragma unroll
    for (int r = 0; r < RELS; ++r) {
        const float* ab = agg2 + ((size_t)r * NODES + n0) * FHID;
        const float* wr = Wl + r * FHID * FOUT + j;
#pragma unroll 1
        for (int k4 = 0; k4 < FHID / 4; ++k4) {
            float4 a[16];
#pragma unroll
            for (int i = 0; i < 16; ++i)
                a[i] = *(const float4*)(ab + (size_t)i * FHID + k4 * 4);
            const float* wp = wr + k4 * 4 * FOUT;
            float w0 = wp[0], w1 = wp[FOUT], w2 = wp[2 * FOUT], w3 = wp[3 * FOUT];
#pragma unroll
            for (int i = 0; i < 16; ++i) {
                acc[i] = fmaf(a[i].x, w0, acc[i]);
                acc[i] = fmaf(a[i].y, w1, acc[i]);
                acc[i] = fmaf(a[i].z, w2, acc[i]);
                acc[i] = fmaf(a[i].w, w3, acc[i]);
            }
        }
    }
    float* ob = out + (size_t)n0 * FOUT + j;
#pragma unroll
    for (int i = 0; i < 16; ++i) ob[(size_t)i * FOUT] = acc[i];
}

extern "C" void kernel_launch(void* const* d_in, const int* in_sizes, int n_in,
                              void* d_out, int out_size, void* d_ws, size_t ws_size,
                              hipStream_t stream) {
    const float* x   = (const float*)d_in[0];   // [N,128]
    const float* W1  = (const float*)d_in[1];   // [3,128,64]
    const float* b1  = (const float*)d_in[2];   // [3,64]
    const float* W2  = (const float*)d_in[3];   // [3,64,64]
    const float* b2  = (const float*)d_in[4];   // [3,64]
    const int*   src = (const int*)d_in[5];     // [3,E]
    const int*   dst = (const int*)d_in[6];     // [3,E]
    float* out = (float*)d_out;                 // [N,64]

    // workspace layout: odI | idI | cursor | offs | partials(1024) | edge_src | outnorm | innorm | A | B
    int*   odI      = (int*)d_ws;
    int*   idI      = odI + SEGS;
    int*   cursor   = idI + SEGS;
    int*   offs     = cursor + SEGS;
    int*   partials = offs + SEGS;
    int*   edge_src = partials + 1024;
    float* outnorm  = (float*)(edge_src + (size_t)RELS * NEDGE);
    float* innorm   = outnorm + SEGS;
    float* A        = innorm + SEGS;                  // [3,N,64] layer-1 h / layer-2 agg
    float* B        = A + (size_t)SEGS * FHID;        // [N,64]   layer-1 output (h1)

    const int EB = (NEDGE + 255) / 256;               // 2344
    const int GB = (NODES / 16 + 3) / 4;              // 782 wave-groups of 16 rows

    // zero odI, idI, cursor (contiguous)
    hipMemsetAsync(odI, 0, 3ull * SEGS * sizeof(int), stream);

    // degrees + norms (shared by both layers)
    deg_kernel<<<dim3(EB, RELS), 256, 0, stream>>>(src, dst, odI, idI);
    norm_kernel<<<(SEGS + 255) / 256, 256, 0, stream>>>(odI, idI, outnorm, innorm);

    // CSR build on dst (shared by both layers)
    scan_sums_kernel<<<NBLK, 256, 0, stream>>>(idI, partials);
    scan_partials_kernel<<<1, 1024, 0, stream>>>(partials);
    scan_write_kernel<<<NBLK, 256, 0, stream>>>(idI, partials, offs);
    fill_kernel<<<dim3(EB, RELS), 256, 0, stream>>>(src, dst, offs, cursor, edge_src);

    // layer 1
    gemm1_kernel<<<dim3(GB, RELS), 256, 0, stream>>>(x, W1, outnorm, A);
    gather1_kernel<<<NODES / 4, 256, 0, stream>>>(A, edge_src, offs, idI, innorm, b1, B);

    // layer 2
    gather2_kernel<<<dim3(NODES / 4, RELS), 256, 0, stream>>>(B, edge_src, offs, idI, outnorm, innorm, A);
    out_kernel<<<GB, 256, 0, stream>>>(A, W2, b2, out);
}